// Round 5
// baseline (609.908 us; speedup 1.0000x reference)
//
#include <hip/hip_runtime.h>

#define BB 4
#define NT 256
#define NZ 384
#define NX 384
#define NREC 128
#define NZX (NZ*NX)        // 147456
#define BNZX (BB*NZX)      // 589824
#define DT 0.001f
#define INV_DH2 0.01f      // 1/(10*10)

#define TILE 48            // interior tile edge
#define HALO 8             // halo width = KSTEP
#define REGN 64            // TILE + 2*HALO
#define NBLK 256           // 8x8 tiles x 4 batches (1 block/CU)
#define NTHR 512           // 8 waves: wave w owns rows 8w..8w+7, lane = col
#define FSTRIDE 16         // flag spread (64 B) -> no line sharing

__global__ void wave_init(unsigned* flags) {
    int i = blockIdx.x * blockDim.x + threadIdx.x;
    if (i < NBLK * FSTRIDE) flags[i] = 0u;
}

__device__ inline float dpp_shl1(float v) {
    return __int_as_float(__builtin_amdgcn_update_dpp(
        0, __float_as_int(v), 0x130 /*WAVE_SHL1*/, 0xf, 0xf, true));
}
__device__ inline float dpp_shr1(float v) {
    return __int_as_float(__builtin_amdgcn_update_dpp(
        0, __float_as_int(v), 0x138 /*WAVE_SHR1*/, 0xf, 0xf, true));
}

__device__ inline unsigned long long pk2(float a, float b) {
    union { float f[2]; unsigned long long u; } t; t.f[0] = a; t.f[1] = b; return t.u;
}
__device__ inline void upk2(unsigned long long v, float& a, float& b) {
    union { unsigned long long u; float f[2]; } t; t.u = v; a = t.f[0]; b = t.f[1];
}

// Exchange protocol (bulk coherence, r5):
//   writer: plain ring stores -> __syncthreads (stores ACKed by XCD L2)
//           -> fence(release, agent)  [buffer_wbl2: dirty L2 -> LLC, bulk]
//           -> relaxed agent flag store
//   reader: relaxed agent poll -> fence(acquire, agent)  [buffer_inv: L1+L2]
//           -> __syncthreads -> plain halo loads (fetch fresh from LLC)
// Per-access sc1 (r0-r4) paid LLC/HBM latency on EVERY frame access; this
// pays one writeback + one invalidate per exchange. Frames (9.4 MB) stay
// LLC-resident; HBM write-through traffic should vanish.

__global__ __launch_bounds__(NTHR)
void wave_tiled(float* __restrict__ ws, const float* __restrict__ vp,
                const float* __restrict__ x,
                const int* __restrict__ src_y, const int* __restrict__ src_x,
                const int* __restrict__ rec_y, const int* __restrict__ rec_x,
                float* __restrict__ y) {
    __shared__ float bnd[2][16][REGN];   // [parity][2*wave+{top,bot}][col]
    __shared__ float recBuf[NREC][8];    // receiver samples, flushed per window
    __shared__ float xs[NT];             // this batch's source trace
    __shared__ int recLoc[NREC], recOut[NREC];
    __shared__ int recCnt;

    unsigned* flags = (unsigned*)(ws + 4*BNZX);

    const int tid = threadIdx.x;
    const int col = tid & 63;
    const int w   = tid >> 6;
    const int r0  = w << 3;
    const int blk = blockIdx.x;
    const int b  = blk >> 6;
    const int tz = (blk >> 3) & 7;
    const int tx = blk & 7;
    const int oz = tz*TILE - HALO, ox = tx*TILE - HALO;
    const int gx = ox + col;
    const int sy = src_y[b], sx = src_x[b];

    if (tid == 0) recCnt = 0;
    for (int k = tid; k < 16*REGN; k += NTHR) ((float*)bnd[0])[k] = 0.f;
    for (int k = tid; k < NT; k += NTHR) xs[k] = x[b*NT + k];
    __syncthreads();
    for (int r = tid; r < NREC; r += NTHR) {
        int ry = rec_y[r], rx = rec_x[r];
        if (ry/TILE == tz && rx/TILE == tx) {
            int p = atomicAdd(&recCnt, 1);
            recLoc[p] = ((ry - oz) << 6) | (rx - ox);
            recOut[p] = b*NREC + r;
        }
    }
    __syncthreads();

    // per-thread receiver ownership cache (cap 4, LDS-loop fallback)
    int myN = 0, myM[4], myP[4];
    bool ovf = false;
    for (int p = 0; p < recCnt; ++p) {
        int rl = recLoc[p];
        if ((rl & 63) == col) {
            int rm = (rl >> 6) - r0;
            if ((unsigned)rm < 8u) {
                if (myN < 4) { myM[myN] = rm; myP[myN] = p; ++myN; }
                else ovf = true;
            }
        }
    }

    // neighbor ids for the sync (lanes 0..7 of wave 0; others self)
    int nbId = blk;
    if (tid < 8) {
        int d = tid + (tid >= 4);            // 0..8 skipping center 4
        int nz2 = tz + d/3 - 1, nx2 = tx + d%3 - 1;
        if ((unsigned)nz2 < 8u && (unsigned)nx2 < 8u)
            nbId = (b << 6) | (nz2 << 3) | nx2;
    }

    // per-thread column state: 8 rows in registers
    float cur[8], prv[8], c2i[8];
    #pragma unroll
    for (int m = 0; m < 8; ++m) {
        cur[m] = 0.f; prv[m] = 0.f;
        const int gz = oz + r0 + m;
        const bool inner = (gz > 0 && gz < NZ-1 && gx > 0 && gx < NX-1);
        const float v = inner ? vp[gz*NX + gx] * DT : 0.f;
        c2i[m] = v * v * INV_DH2;    // 0 at edges -> lap auto-masked
    }
    const bool srcCol = (gx == sx);
    const int  srcM   = sy - oz - r0;
    const int  iuUp   = (2*w-1 < 0) ? 0 : 2*w-1;
    const int  iuDn   = (2*w+2 > 15) ? 15 : 2*w+2;
    __syncthreads();

    #pragma unroll 1
    for (int t = 0; t < NT; ++t) {
        const int pr = t & 1, pw = pr ^ 1;
        const float upB = bnd[pr][iuUp][col];
        const float dnB = bnd[pr][iuDn][col];

        float hn[8];
        #pragma unroll
        for (int m = 0; m < 8; ++m) {
            const float ce = cur[m];
            const float up = (m == 0) ? upB : cur[m-1];
            const float dn = (m == 7) ? dnB : cur[m+1];
            const float lf = dpp_shl1(ce);
            const float rt = dpp_shr1(ce);
            const float s  = (up + dn) + (lf + rt);
            hn[m] = fmaf(2.f, ce, -prv[m]) + c2i[m] * fmaf(-4.f, ce, s);
        }
        #pragma unroll
        for (int m = 0; m < 8; ++m) { prv[m] = cur[m]; cur[m] = hn[m]; }

        if (srcCol && (unsigned)srcM < 8u) {
            const float xv = xs[t];
            #pragma unroll
            for (int m = 0; m < 8; ++m) if (m == srcM) cur[m] += xv;
        }
        // receiver sampling -> LDS buffer (no global ops in the step loop)
        {
            const int s2 = t & 7;
            if (ovf) {
                for (int p = 0; p < recCnt; ++p) {
                    int rl = recLoc[p];
                    if ((rl & 63) == col) {
                        int rm = (rl >> 6) - r0;
                        if ((unsigned)rm < 8u) {
                            float v = cur[0];
                            #pragma unroll
                            for (int m = 1; m < 8; ++m) if (rm == m) v = cur[m];
                            recBuf[p][s2] = v;
                        }
                    }
                }
            } else {
                #pragma unroll
                for (int k = 0; k < 4; ++k) {
                    if (k < myN) {
                        float v = cur[0];
                        #pragma unroll
                        for (int m = 1; m < 8; ++m) if (myM[k] == m) v = cur[m];
                        recBuf[myP[k]][s2] = v;
                    }
                }
            }
        }
        bnd[pw][2*w  ][col] = cur[0];
        bnd[pw][2*w+1][col] = cur[7];

        if ((t & 7) == 7) {
            const int o = t >> 3;
            const bool exch = (t < NT-1);
            unsigned long long* G = nullptr;
            if (exch) {
                G = (unsigned long long*)ws + (size_t)(o & 1) * BNZX;  // ping-pong
                // plain stores of the ring between depth HALO and 2*HALO
                const bool colF = (col >= HALO   && col < REGN-HALO);
                const bool colM = (col >= 2*HALO && col < REGN-2*HALO);
                #pragma unroll
                for (int m = 0; m < 8; ++m) {
                    const int i = r0 + m;
                    const bool rowF = (i >= HALO   && i < REGN-HALO);
                    const bool rowM = (i >= 2*HALO && i < REGN-2*HALO);
                    if (colF && rowF && !(colM && rowM)) {
                        const size_t g = (size_t)b*NZX + (size_t)(oz+i)*NX + gx;
                        G[g] = pk2(cur[m], prv[m]);
                    }
                }
            }
            __syncthreads();   // all waves' ring stores ACKed by L2; recBuf visible
            if (exch && tid == 0) {
                __builtin_amdgcn_fence(__ATOMIC_RELEASE, "agent");  // wbl2: L2->LLC
                __hip_atomic_store(&flags[blk * FSTRIDE], (unsigned)(o + 1),
                                   __ATOMIC_RELAXED, __HIP_MEMORY_SCOPE_AGENT);
            }
            // receiver flush overlaps the neighbor wait
            for (int k = tid; k < recCnt*8; k += NTHR) {
                int p = k >> 3, s2 = k & 7;
                y[(size_t)((o<<3)+s2)*(BB*NREC) + recOut[p]] = recBuf[p][s2];
            }
            if (exch) {
                const unsigned gen = (unsigned)(o + 1);
                if (tid < 64) {
                    for (;;) {
                        unsigned f = __hip_atomic_load(&flags[nbId * FSTRIDE],
                                         __ATOMIC_RELAXED, __HIP_MEMORY_SCOPE_AGENT);
                        if (__all(f >= gen)) break;
                        __builtin_amdgcn_s_sleep(1);
                    }
                    __builtin_amdgcn_fence(__ATOMIC_ACQUIRE, "agent"); // inv L1+L2
                }
                __syncthreads();   // fence done before any wave's halo loads
                const bool colH = (col < HALO || col >= REGN-HALO);
                const bool gxIn = (gx >= 0 && gx < NX);
                #pragma unroll
                for (int m = 0; m < 8; ++m) {
                    const int i = r0 + m;
                    if (colH || i < HALO || i >= REGN-HALO) {
                        const int gz = oz + i;
                        if (gxIn && gz >= 0 && gz < NZ) {
                            unsigned long long v =
                                G[(size_t)b*NZX + (size_t)gz*NX + gx];
                            upk2(v, cur[m], prv[m]);
                        } else { cur[m] = 0.f; prv[m] = 0.f; }
                    }
                }
                bnd[pw][2*w  ][col] = cur[0];
                bnd[pw][2*w+1][col] = cur[7];
            }
        }
        __syncthreads();
    }
}

extern "C" void kernel_launch(void* const* d_in, const int* in_sizes, int n_in,
                              void* d_out, int out_size, void* d_ws, size_t ws_size,
                              hipStream_t stream) {
    const float* x     = (const float*)d_in[0];
    const float* vp    = (const float*)d_in[1];
    const int*   src_y = (const int*)d_in[2];
    const int*   src_x = (const int*)d_in[3];
    const int*   rec_y = (const int*)d_in[4];
    const int*   rec_x = (const int*)d_in[5];
    float* y  = (float*)d_out;
    float* ws = (float*)d_ws;   // 2 packed u64 frames (== 4*BNZX floats) + flags

    wave_init<<<(NBLK*FSTRIDE + 255)/256, 256, 0, stream>>>((unsigned*)(ws + 4*BNZX));
    wave_tiled<<<NBLK, NTHR, 0, stream>>>(ws, vp, x, src_y, src_x, rec_y, rec_x, y);
}

// Round 6
// 331.316 us; speedup vs baseline: 1.8409x; 1.8409x over previous
//
#include <hip/hip_runtime.h>

#define BB 4
#define NT 256
#define NZ 384
#define NX 384
#define NREC 128
#define NZX (NZ*NX)        // 147456
#define BNZX (BB*NZX)      // 589824
#define DT 0.001f
#define INV_DH2 0.01f      // 1/(10*10)

#define TILE 48            // interior tile edge
#define HALO 8             // halo width = KSTEP
#define REGN 64            // TILE + 2*HALO
#define NBLK 256           // 8x8 tiles x 4 batches (1 block/CU)
#define NTHR 512           // 8 waves: wave w owns rows 8w..8w+7, lane = col
#define FSTRIDE 16         // flag spread (64 B) -> no line sharing

typedef __attribute__((ext_vector_type(4))) float f32x4;

__global__ void wave_init(unsigned* flags) {
    int i = blockIdx.x * blockDim.x + threadIdx.x;
    if (i < NBLK * FSTRIDE) flags[i] = 0u;
}

__device__ inline float dpp_shl1(float v) {
    return __int_as_float(__builtin_amdgcn_update_dpp(
        0, __float_as_int(v), 0x130 /*WAVE_SHL1*/, 0xf, 0xf, true));
}
__device__ inline float dpp_shr1(float v) {
    return __int_as_float(__builtin_amdgcn_update_dpp(
        0, __float_as_int(v), 0x138 /*WAVE_SHR1*/, 0xf, 0xf, true));
}

// ---- exchange geometry -------------------------------------------------
// Ring (stored): owned outer ring, region rows/cols [8,56) minus [16,48)^2.
// 1280 cells = 320 aligned 4-col groups. Stage index == 4*group.
__device__ inline int ridx(int i, int c) {
    if (c >= 8 && c < 56) {
        if (i >= 8  && i < 16) return (i-8)*48 + (c-8);
        if (i >= 48 && i < 56) return 384 + (i-48)*48 + (c-8);
    }
    if (i >= 16 && i < 48) {
        if (c >= 8  && c < 16) return 768 + (i-16)*16 + (c-8);
        if (c >= 48 && c < 56) return 768 + (i-16)*16 + 8 + (c-48);
    }
    return -1;
}
__device__ inline void sdec(int g, int& i, int& c0) {
    if (g < 96)       { i = 8 + g/12;              c0 = 8 + (g%12)*4; }
    else if (g < 192) { int h = g-96;  i = 48 + h/12; c0 = 8 + (h%12)*4; }
    else              { int h = g-192; i = 16 + h/4;  int q = h & 3;
                        c0 = (q < 2) ? 8 + q*4 : 48 + (q-2)*4; }
}
// Halo (loaded): region rows [0,8) & [56,64) full width + cols [0,8) & [56,64)
// for rows [8,56).  1792 cells = 448 aligned groups. Stage index == 4*group.
__device__ inline int hidx(int i, int c) {
    if (i < 8)   return i*64 + c;
    if (i >= 56) return 512 + (i-56)*64 + c;
    if (c < 8)   return 1024 + (i-8)*16 + c;
    if (c >= 56) return 1024 + (i-8)*16 + 8 + (c-56);
    return -1;
}
__device__ inline void ldec(int g, int& i, int& c0) {
    if (g < 128)      { i = g/16;                  c0 = (g%16)*4; }
    else if (g < 256) { int h = g-128; i = 56 + h/16; c0 = (h%16)*4; }
    else              { int s = g-256; i = 8 + s/4;   int q = s & 3;
                        c0 = (q < 2) ? q*4 : 56 + (q-2)*4; }
}

__global__ __launch_bounds__(NTHR)
void wave_tiled(float* __restrict__ ws, const float* __restrict__ vp,
                const float* __restrict__ x,
                const int* __restrict__ src_y, const int* __restrict__ src_x,
                const int* __restrict__ rec_y, const int* __restrict__ rec_x,
                float* __restrict__ y) {
    __shared__ float bnd[2][16][REGN];   // [parity][2*wave+{top,bot}][col]
    __shared__ float recBuf[NREC][8];    // receiver samples, flushed per window
    __shared__ float xs[NT];             // this batch's source trace
    __shared__ int recLoc[NREC], recOut[NREC];
    __shared__ int recCnt;
    __shared__ alignas(16) float stage[2][1792];  // [field][cells] marshal buffer

    unsigned* flags = (unsigned*)(ws + 4*BNZX);

    const int tid = threadIdx.x;
    const int col = tid & 63;
    const int w   = tid >> 6;
    const int r0  = w << 3;
    const int blk = blockIdx.x;
    const int b  = blk >> 6;
    const int tz = (blk >> 3) & 7;
    const int tx = blk & 7;
    const int oz = tz*TILE - HALO, ox = tx*TILE - HALO;
    const int gx = ox + col;
    const int sy = src_y[b], sx = src_x[b];

    if (tid == 0) recCnt = 0;
    for (int k = tid; k < 16*REGN; k += NTHR) ((float*)bnd[0])[k] = 0.f;
    for (int k = tid; k < NT; k += NTHR) xs[k] = x[b*NT + k];
    __syncthreads();
    for (int r = tid; r < NREC; r += NTHR) {
        int ry = rec_y[r], rx = rec_x[r];
        if (ry/TILE == tz && rx/TILE == tx) {
            int p = atomicAdd(&recCnt, 1);
            recLoc[p] = ((ry - oz) << 6) | (rx - ox);
            recOut[p] = b*NREC + r;
        }
    }
    __syncthreads();

    // per-thread receiver ownership cache (cap 4, LDS-loop fallback)
    int myN = 0, myM[4], myP[4];
    bool ovf = false;
    for (int p = 0; p < recCnt; ++p) {
        int rl = recLoc[p];
        if ((rl & 63) == col) {
            int rm = (rl >> 6) - r0;
            if ((unsigned)rm < 8u) {
                if (myN < 4) { myM[myN] = rm; myP[myN] = p; ++myN; }
                else ovf = true;
            }
        }
    }

    // neighbor ids for the sync (lanes 0..7 of wave 0; others self)
    int nbId = blk;
    if (tid < 8) {
        int d = tid + (tid >= 4);            // 0..8 skipping center 4
        int nz2 = tz + d/3 - 1, nx2 = tx + d%3 - 1;
        if ((unsigned)nz2 < 8u && (unsigned)nx2 < 8u)
            nbId = (b << 6) | (nz2 << 3) | nx2;
    }

    // per-thread column state: 8 rows in registers
    float cur[8], prv[8], c2i[8];
    #pragma unroll
    for (int m = 0; m < 8; ++m) {
        cur[m] = 0.f; prv[m] = 0.f;
        const int gz = oz + r0 + m;
        const bool inner = (gz > 0 && gz < NZ-1 && gx > 0 && gx < NX-1);
        const float v = inner ? vp[gz*NX + gx] * DT : 0.f;
        c2i[m] = v * v * INV_DH2;    // 0 at edges -> lap auto-masked
    }
    const bool srcCol = (gx == sx);
    const int  srcM   = sy - oz - r0;
    const int  iuUp   = (2*w-1 < 0) ? 0 : 2*w-1;
    const int  iuDn   = (2*w+2 > 15) ? 15 : 2*w+2;
    __syncthreads();

    #pragma unroll 1
    for (int t = 0; t < NT; ++t) {
        const int pr = t & 1, pw = pr ^ 1;
        const float upB = bnd[pr][iuUp][col];
        const float dnB = bnd[pr][iuDn][col];

        float hn[8];
        #pragma unroll
        for (int m = 0; m < 8; ++m) {
            const float ce = cur[m];
            const float up = (m == 0) ? upB : cur[m-1];
            const float dn = (m == 7) ? dnB : cur[m+1];
            const float lf = dpp_shl1(ce);
            const float rt = dpp_shr1(ce);
            const float s  = (up + dn) + (lf + rt);
            hn[m] = fmaf(2.f, ce, -prv[m]) + c2i[m] * fmaf(-4.f, ce, s);
        }
        #pragma unroll
        for (int m = 0; m < 8; ++m) { prv[m] = cur[m]; cur[m] = hn[m]; }

        if (srcCol && (unsigned)srcM < 8u) {
            const float xv = xs[t];
            #pragma unroll
            for (int m = 0; m < 8; ++m) if (m == srcM) cur[m] += xv;
        }
        // receiver sampling -> LDS buffer (no global ops in the step loop)
        {
            const int s2 = t & 7;
            if (ovf) {
                for (int p = 0; p < recCnt; ++p) {
                    int rl = recLoc[p];
                    if ((rl & 63) == col) {
                        int rm = (rl >> 6) - r0;
                        if ((unsigned)rm < 8u) {
                            float v = cur[0];
                            #pragma unroll
                            for (int m = 1; m < 8; ++m) if (rm == m) v = cur[m];
                            recBuf[p][s2] = v;
                        }
                    }
                }
            } else {
                #pragma unroll
                for (int k = 0; k < 4; ++k) {
                    if (k < myN) {
                        float v = cur[0];
                        #pragma unroll
                        for (int m = 1; m < 8; ++m) if (myM[k] == m) v = cur[m];
                        recBuf[myP[k]][s2] = v;
                    }
                }
            }
        }
        bnd[pw][2*w  ][col] = cur[0];
        bnd[pw][2*w+1][col] = cur[7];

        if ((t & 7) == 7) {
            const int o = t >> 3;
            const bool exch = (t < NT-1);
            float* F0 = ws + (size_t)(o & 1) * 2*BNZX;   // ping-pong frame pair
            float* F1 = F0 + BNZX;

            if (exch) {
                // scatter ring cells (registers) -> stage (LDS)
                #pragma unroll
                for (int m = 0; m < 8; ++m) {
                    int r = ridx(r0 + m, col);
                    if (r >= 0) { stage[0][r] = cur[m]; stage[1][r] = prv[m]; }
                }
            }
            __syncthreads();   // stage + recBuf visible
            if (exch) {
                // cooperative vectorized sc1 stores: 640 dwordx4 groups
                {   // slot A: k = tid  (f = tid/320, g = tid%320)
                    const int f = (tid >= 320), g = tid - (f ? 320 : 0);
                    int i, c0; sdec(g, i, c0);
                    float* p = (f ? F1 : F0) +
                        ((size_t)b*NZX + (size_t)(oz+i)*NX + (ox+c0));
                    f32x4 v = *(const f32x4*)&stage[f][4*g];
                    asm volatile("global_store_dwordx4 %0, %1, off sc1"
                                 :: "v"(p), "v"(v) : "memory");
                }
                if (tid < 128) {  // slot B: k = tid+512 -> f=1, g = tid+192
                    const int g = tid + 192;
                    int i, c0; sdec(g, i, c0);
                    float* p = F1 + ((size_t)b*NZX + (size_t)(oz+i)*NX + (ox+c0));
                    f32x4 v = *(const f32x4*)&stage[1][4*g];
                    asm volatile("global_store_dwordx4 %0, %1, off sc1"
                                 :: "v"(p), "v"(v) : "memory");
                }
                asm volatile("s_waitcnt vmcnt(0)" ::: "memory");  // at LLC
            }
            __syncthreads();   // every wave's ring stores drained
            if (exch && tid == 0)
                __hip_atomic_store(&flags[blk * FSTRIDE], (unsigned)(o + 1),
                                   __ATOMIC_RELAXED, __HIP_MEMORY_SCOPE_AGENT);
            // receiver flush overlaps the neighbor wait
            for (int k = tid; k < recCnt*8; k += NTHR) {
                int p = k >> 3, s2 = k & 7;
                y[(size_t)((o<<3)+s2)*(BB*NREC) + recOut[p]] = recBuf[p][s2];
            }
            if (exch) {
                const unsigned gen = (unsigned)(o + 1);
                if (tid < 64) {
                    for (;;) {
                        unsigned f = __hip_atomic_load(&flags[nbId * FSTRIDE],
                                         __ATOMIC_RELAXED, __HIP_MEMORY_SCOPE_AGENT);
                        if (__all(f >= gen)) break;
                        __builtin_amdgcn_s_sleep(1);
                    }
                }
                __syncthreads();   // all neighbors arrived

                // cooperative vectorized sc1 loads: 896 dwordx4 groups.
                // slot A: k=tid (fA = tid/448); slot B: k=tid+512 (f=1) for tid<384.
                const int fA = (tid >= 448), gA = tid - (fA ? 448 : 0);
                int iA, cA; ldec(gA, iA, cA);
                const int gzA = oz + iA, gcA = ox + cA;
                const bool inA = (gzA >= 0 && gzA < NZ && gcA >= 0 && gcA <= NX-4);
                const float* bseA = fA ? F1 : F0;
                const float* pA = inA ?
                    bseA + ((size_t)b*NZX + (size_t)gzA*NX + gcA) : bseA;

                const bool hasB = (tid < 384);
                const int gB = tid + 64;              // f=1, g in [64,448)
                int iB, cB; ldec(gB, iB, cB);
                const int gzB = oz + iB, gcB = ox + cB;
                const bool inB = hasB && (gzB >= 0 && gzB < NZ &&
                                          gcB >= 0 && gcB <= NX-4);
                const float* pB = inB ?
                    F1 + ((size_t)b*NZX + (size_t)gzB*NX + gcB) : F1;

                f32x4 vA, vB;
                // single asm block: issue both loads, waitcnt inside -> no
                // chance of the compiler copying an in-flight dest register.
                asm volatile("global_load_dwordx4 %0, %2, off sc1\n\t"
                             "global_load_dwordx4 %1, %3, off sc1\n\t"
                             "s_waitcnt vmcnt(0)"
                             : "=&v"(vA), "=&v"(vB)
                             : "v"(pA), "v"(pB)
                             : "memory");
                __builtin_amdgcn_sched_barrier(0);
                const f32x4 z = {0.f, 0.f, 0.f, 0.f};
                if (!inA) vA = z;
                if (!inB) vB = z;
                *(f32x4*)&stage[fA][4*gA] = vA;
                if (hasB) *(f32x4*)&stage[1][4*gB] = vB;
                __syncthreads();   // stage halo complete

                // gather halo cells from stage (out-of-domain already 0)
                #pragma unroll
                for (int m = 0; m < 8; ++m) {
                    int h = hidx(r0 + m, col);
                    if (h >= 0) { cur[m] = stage[0][h]; prv[m] = stage[1][h]; }
                }
                bnd[pw][2*w  ][col] = cur[0];
                bnd[pw][2*w+1][col] = cur[7];
            }
        }
        __syncthreads();
    }
}

extern "C" void kernel_launch(void* const* d_in, const int* in_sizes, int n_in,
                              void* d_out, int out_size, void* d_ws, size_t ws_size,
                              hipStream_t stream) {
    const float* x     = (const float*)d_in[0];
    const float* vp    = (const float*)d_in[1];
    const int*   src_y = (const int*)d_in[2];
    const int*   src_x = (const int*)d_in[3];
    const int*   rec_y = (const int*)d_in[4];
    const int*   rec_x = (const int*)d_in[5];
    float* y  = (float*)d_out;
    float* ws = (float*)d_ws;   // 4*BNZX frame floats + 256*16 flag words

    wave_init<<<(NBLK*FSTRIDE + 255)/256, 256, 0, stream>>>((unsigned*)(ws + 4*BNZX));
    wave_tiled<<<NBLK, NTHR, 0, stream>>>(ws, vp, x, src_y, src_x, rec_y, rec_x, y);
}